// Round 7
// baseline (1055.909 us; speedup 1.0000x reference)
//
#include <hip/hip_runtime.h>
#include <hip/hip_bf16.h>

#define HID 50
#define FOURH 200
#define TSTEPS 2048
#define NBATCH 1024

typedef _Float16 v2h __attribute__((ext_vector_type(2)));

#define LOG2E 1.44269504f

__device__ __forceinline__ float frcp(float x)  { return __builtin_amdgcn_rcpf(x); }
__device__ __forceinline__ float fexp2(float x) { return __builtin_amdgcn_exp2f(x); }

__device__ __forceinline__ float fast_sigmoid(float x) {
    return frcp(1.0f + fexp2(-LOG2E * x));   // NaN-free both tails
}
__device__ __forceinline__ float fast_tanh(float x) {
    return 1.0f - 2.0f * frcp(fexp2((2.0f * LOG2E) * x) + 1.0f);  // saturating
}
__device__ __forceinline__ v2h bc_v2h(unsigned int u) {
    return __builtin_bit_cast(v2h, u);
}

// One block (256 thr, 4 waves) per batch; grid 1024 -> 4 blocks/CU so each
// SIMD holds 4 waves of INDEPENDENT batches (the latency-hiding R3 lacked).
// Thread tid<200 owns gate column tid (gate g=tid/50, unit u=tid%50): 25
// v_dot2_f32_f16 per step (Wh column pre-packed half2 in VGPRs, h broadcast
// from LDS as 7x b128). Gate phase (5 transcendentals, c/h update) runs on
// wave 0 only; other blocks hide that serial chain. zbuf[4][52] keeps both
// write (consecutive) and read (stride 52, <=2-way) conflict-free.
__global__ __launch_bounds__(256, 4)
void lstm_col_kernel(const float* __restrict__ x,
                     const float* __restrict__ Wx,
                     const float* __restrict__ Wh,
                     const float* __restrict__ bias,
                     const float* __restrict__ Wd,
                     const float* __restrict__ bd,
                     float* __restrict__ out) {
    const int b   = blockIdx.x;
    const int tid = threadIdx.x;
    const bool is_col  = (tid < FOURH);
    const bool is_unit = (tid < HID);
    const int u = is_col ? (tid % HID) : 0;   // unit index of this column
    const int g = is_col ? (tid / HID) : 0;   // gate index (0:i 1:f 2:g 3:o)

    __shared__ __align__(16) float    xs[TSTEPS + 4];
    __shared__ __align__(16) _Float16 hbuf[56];    // h (f16), [50..55] zero pad
    __shared__ __align__(16) float    zbuf[4][52]; // z per gate, padded rows

    // Stage x (coalesced float4).
    const float4* xb4 = (const float4*)(x + (size_t)b * TSTEPS);
    float4* xs4 = (float4*)xs;
    #pragma unroll
    for (int i = tid; i < TSTEPS / 4; i += 256) xs4[i] = xb4[i];
    if (tid == 0) xs[TSTEPS] = 0.0f;
    if (tid < 56) hbuf[tid] = (_Float16)0.0f;

    // Column weights: Wh[:,col] packed half2 along k (25 pairs).
    v2h w[25];
    float wx_c = 0.0f, b_c = 0.0f;
    if (is_col) {
        #pragma unroll
        for (int k2 = 0; k2 < 25; ++k2) {
            w[k2] = v2h{(_Float16)Wh[(2 * k2) * FOURH + tid],
                        (_Float16)Wh[(2 * k2 + 1) * FOURH + tid]};
        }
        wx_c = Wx[tid];
        b_c  = bias[tid];
    } else {
        #pragma unroll
        for (int k2 = 0; k2 < 25; ++k2) w[k2] = v2h{(_Float16)0.f, (_Float16)0.f};
    }

    float c = 0.0f;
    float h = 0.0f;   // unit threads' register copy of h_u
    __syncthreads();

    const uint4* hb4 = (const uint4*)hbuf;   // 7 x b128 = 56 halves

    for (int t = 0; t < TSTEPS; ++t) {
        // ---- dot phase: all 200 column threads ----
        if (is_col) {
            const float xt = xs[t];
            const uint4 q0 = hb4[0], q1 = hb4[1], q2 = hb4[2], q3 = hb4[3];
            const uint4 q4 = hb4[4], q5 = hb4[5], q6 = hb4[6];
            // 4 independent dot2 chains (depth 7/6/6/6).
            float a0 = 0.f, a1 = 0.f, a2 = 0.f, a3 = 0.f;
            a0 = __builtin_amdgcn_fdot2(w[0],  bc_v2h(q0.x), a0, false);
            a1 = __builtin_amdgcn_fdot2(w[1],  bc_v2h(q0.y), a1, false);
            a2 = __builtin_amdgcn_fdot2(w[2],  bc_v2h(q0.z), a2, false);
            a3 = __builtin_amdgcn_fdot2(w[3],  bc_v2h(q0.w), a3, false);
            a0 = __builtin_amdgcn_fdot2(w[4],  bc_v2h(q1.x), a0, false);
            a1 = __builtin_amdgcn_fdot2(w[5],  bc_v2h(q1.y), a1, false);
            a2 = __builtin_amdgcn_fdot2(w[6],  bc_v2h(q1.z), a2, false);
            a3 = __builtin_amdgcn_fdot2(w[7],  bc_v2h(q1.w), a3, false);
            a0 = __builtin_amdgcn_fdot2(w[8],  bc_v2h(q2.x), a0, false);
            a1 = __builtin_amdgcn_fdot2(w[9],  bc_v2h(q2.y), a1, false);
            a2 = __builtin_amdgcn_fdot2(w[10], bc_v2h(q2.z), a2, false);
            a3 = __builtin_amdgcn_fdot2(w[11], bc_v2h(q2.w), a3, false);
            a0 = __builtin_amdgcn_fdot2(w[12], bc_v2h(q3.x), a0, false);
            a1 = __builtin_amdgcn_fdot2(w[13], bc_v2h(q3.y), a1, false);
            a2 = __builtin_amdgcn_fdot2(w[14], bc_v2h(q3.z), a2, false);
            a3 = __builtin_amdgcn_fdot2(w[15], bc_v2h(q3.w), a3, false);
            a0 = __builtin_amdgcn_fdot2(w[16], bc_v2h(q4.x), a0, false);
            a1 = __builtin_amdgcn_fdot2(w[17], bc_v2h(q4.y), a1, false);
            a2 = __builtin_amdgcn_fdot2(w[18], bc_v2h(q4.z), a2, false);
            a3 = __builtin_amdgcn_fdot2(w[19], bc_v2h(q4.w), a3, false);
            a0 = __builtin_amdgcn_fdot2(w[20], bc_v2h(q5.x), a0, false);
            a1 = __builtin_amdgcn_fdot2(w[21], bc_v2h(q5.y), a1, false);
            a2 = __builtin_amdgcn_fdot2(w[22], bc_v2h(q5.z), a2, false);
            a3 = __builtin_amdgcn_fdot2(w[23], bc_v2h(q5.w), a3, false);
            a0 = __builtin_amdgcn_fdot2(w[24], bc_v2h(q6.x), a0, false);
            zbuf[g][u] = fmaf(xt, wx_c, b_c) + (a0 + a1) + (a2 + a3);
        }
        __syncthreads();
        // ---- gate phase: wave 0, unit threads only ----
        if (is_unit) {
            const float zi = zbuf[0][tid];
            const float zf = zbuf[1][tid];
            const float zg = zbuf[2][tid];
            const float zo = zbuf[3][tid];
            const float ig = fast_sigmoid(zi);
            const float fg = fast_sigmoid(zf);
            const float gg = fast_tanh(zg);
            const float og = fast_sigmoid(zo);
            c = fmaf(fg, c, ig * gg);
            h = og * fast_tanh(c);
            hbuf[tid] = (_Float16)h;
        }
        __syncthreads();
    }

    // out[b] = h_T . Wd + bd (unit threads hold fp32 h; wave 0 reduce)
    if (tid < 64) {
        float v = is_unit ? h * Wd[tid] : 0.0f;
        #pragma unroll
        for (int off = 32; off > 0; off >>= 1) v += __shfl_down(v, off);
        if (tid == 0) out[b] = v + bd[0];
    }
}

extern "C" void kernel_launch(void* const* d_in, const int* in_sizes, int n_in,
                              void* d_out, int out_size, void* d_ws, size_t ws_size,
                              hipStream_t stream) {
    const float* x    = (const float*)d_in[0];  // [1024, 2048, 1]
    const float* Wx   = (const float*)d_in[1];  // [1, 200]
    const float* Wh   = (const float*)d_in[2];  // [50, 200]
    const float* bias = (const float*)d_in[3];  // [200]
    const float* Wd   = (const float*)d_in[4];  // [50, 1]
    const float* bd   = (const float*)d_in[5];  // [1]
    float* out = (float*)d_out;                 // [1024, 1]

    lstm_col_kernel<<<dim3(NBATCH), dim3(256), 0, stream>>>(
        x, Wx, Wh, bias, Wd, bd, out);
}